// Round 3
// baseline (216.722 us; speedup 1.0000x reference)
//
#include <hip/hip_runtime.h>

#define IN_DIM 128
#define OUT_DIM 32
#define DEG 16
#define EPS 1e-8f

// Kernel 1: thread = node. acc[32] lives in VGPRs; W is read with
// wave-uniform addresses -> scalar loads (SGPR operands in v_fmac), so the
// inner loop is pure VALU FMA. h row streamed 64 B (one cache line) per
// chunk with one-chunk software prefetch. No LDS, no shuffles.
__global__ __launch_bounds__(64) void gemm_norm_kernel(
    const float* __restrict__ h, const float* __restrict__ W,
    float* __restrict__ zh, float* __restrict__ nrm, int N) {
  int n = blockIdx.x * 64 + threadIdx.x;
  const bool active = (n < N);
  if (!active) n = N - 1;  // clamped read; stores guarded below
  const float4* __restrict__ hp = (const float4*)(h + (size_t)n * IN_DIM);

  float acc[OUT_DIM];
#pragma unroll
  for (int o = 0; o < OUT_DIM; ++o) acc[o] = 0.f;

  float4 buf[4];
#pragma unroll
  for (int j = 0; j < 4; ++j) buf[j] = hp[j];

  for (int c = 0; c < IN_DIM / 16; ++c) {  // 8 chunks of 16 k-values
    float hr[16];
#pragma unroll
    for (int j = 0; j < 4; ++j) {
      hr[4 * j + 0] = buf[j].x;
      hr[4 * j + 1] = buf[j].y;
      hr[4 * j + 2] = buf[j].z;
      hr[4 * j + 3] = buf[j].w;
    }
    if (c + 1 < IN_DIM / 16) {
#pragma unroll
      for (int j = 0; j < 4; ++j) buf[j] = hp[(c + 1) * 4 + j];  // prefetch
    }
#pragma unroll
    for (int o = 0; o < OUT_DIM; ++o) {
      const float* __restrict__ wr = W + o * IN_DIM + c * 16;  // wave-uniform
#pragma unroll
      for (int j = 0; j < 16; ++j) acc[o] = fmaf(hr[j], wr[j], acc[o]);
    }
  }

  float ss = 0.f;
#pragma unroll
  for (int o = 0; o < OUT_DIM; ++o) ss = fmaf(acc[o], acc[o], ss);
  const float ns = sqrtf(ss);
  const float inv = 1.0f / fmaxf(ns, EPS);

  if (active) {
    float4* __restrict__ zp = (float4*)(zh + (size_t)n * OUT_DIM);
#pragma unroll
    for (int j = 0; j < 8; ++j) {
      float4 t;
      t.x = acc[4 * j + 0] * inv;
      t.y = acc[4 * j + 1] * inv;
      t.z = acc[4 * j + 2] * inv;
      t.w = acc[4 * j + 3] * inv;
      zp[j] = t;
    }
    nrm[n] = ns;
  }
}

// Kernel 2: half-wave (32 lanes, lane = o) per node. All 16 src indices are
// loaded lane-parallel in ONE instruction, all 16 row-gathers issued up
// front (16 outstanding loads), nrm gathered lane-parallel and re-broadcast
// by shuffle at use. Scores e = beta*(cos-1) are bounded in [-2b, 0], so
// softmax needs no max pass (verified R2: absmax 3.9e-3).
__global__ __launch_bounds__(256) void edge_kernel(
    const float* __restrict__ zh, const float* __restrict__ nrm,
    const int* __restrict__ src, const float* __restrict__ beta_p,
    float* __restrict__ out, int N) {
  const int o = threadIdx.x & 31;
  const int n = (int)((blockIdx.x * 256 + threadIdx.x) >> 5);
  if (n >= N) return;

  const float beta = *beta_p;
  const float zd = zh[(size_t)n * OUT_DIM + o];

  // lanes e=0..15 of each half-wave carry s_e and nrm[s_e] (lanes 16..31 dup)
  const int s_lane = src[(size_t)n * DEG + (o & 15)];
  const float nrm_lane = nrm[s_lane];
  const int sb = threadIdx.x & 32;  // shuffle base for this half-wave

  int se[DEG];
#pragma unroll
  for (int e = 0; e < DEG; ++e) se[e] = __shfl(s_lane, sb + e);

  float zse[DEG];
#pragma unroll
  for (int e = 0; e < DEG; ++e)
    zse[e] = zh[(size_t)se[e] * OUT_DIM + o];  // 16 coalesced gathers in flight

  float denom = 0.f, acc = 0.f;
#pragma unroll
  for (int e = 0; e < DEG; ++e) {
    float p = zse[e] * zd;
    p += __shfl_xor(p, 16);
    p += __shfl_xor(p, 8);
    p += __shfl_xor(p, 4);
    p += __shfl_xor(p, 2);
    p += __shfl_xor(p, 1);  // p = cos for edge e, all lanes
    const float ex = __expf(beta * (p - 1.0f));
    denom += ex;
    acc = fmaf(ex * __shfl(nrm_lane, sb + e), zse[e], acc);
  }
  out[(size_t)n * OUT_DIM + o] = acc / denom;
}

extern "C" void kernel_launch(void* const* d_in, const int* in_sizes, int n_in,
                              void* d_out, int out_size, void* d_ws, size_t ws_size,
                              hipStream_t stream) {
  const float* h    = (const float*)d_in[0];
  const float* W    = (const float*)d_in[1];
  const float* beta = (const float*)d_in[2];
  const int*   src  = (const int*)d_in[3];
  // d_in[4] = dst == arange(E)//DEG -> node n owns edges [n*DEG, (n+1)*DEG)

  const int N = in_sizes[0] / IN_DIM;

  float* zh  = (float*)d_ws;              // N*32 floats = 12.8 MB
  float* nrm = zh + (size_t)N * OUT_DIM;  // N floats

  // K1: thread per node, 64-thread blocks (fine-grained for CU balance)
  const int bl1 = (N + 63) / 64;
  gemm_norm_kernel<<<bl1, 64, 0, stream>>>(h, W, zh, nrm, N);

  // K2: half-wave per node, 8 nodes per 256-thread block
  const int bl2 = (N + 7) / 8;
  edge_kernel<<<bl2, 256, 0, stream>>>(zh, nrm, src, beta, (float*)d_out, N);
}

// Round 4
// 139.130 us; speedup vs baseline: 1.5577x; 1.5577x over previous
//
#include <hip/hip_runtime.h>

#define IN_DIM 128
#define OUT_DIM 32
#define DEG 16
#define EPS 1e-8f
#define TN 64     // nodes per K1 block
#define HSTR 129  // odd LDS row stride -> conflict-free b32 reads

// ds_swizzle xor-mask patterns (BitMode: (xor<<10)|0x1F), 32-lane domain
#define SWZ(x, p) __int_as_float(__builtin_amdgcn_ds_swizzle(__float_as_int(x), (p)))

// Kernel 1: z = h @ W^T (raw, unnormalized) + inv_nrm = 1/max(||z||,eps).
// Block 256 = 4 waves, tile = 64 nodes. Stage h tile in LDS (coalesced
// global float4 reads, b32 writes). Wave w computes outputs [8w, 8w+8) for
// all 64 nodes (lane = node): acc[8] in VGPRs (no spill), W addresses are
// wave-uniform -> scalar loads on the scalar pipe.
__global__ __launch_bounds__(256) void gemm_norm_kernel(
    const float* __restrict__ h, const float* __restrict__ W,
    float* __restrict__ z, float* __restrict__ inv_nrm, int N) {
  __shared__ float sh[TN * HSTR];  // 33 KB
  __shared__ float ssq[4][TN];

  const int tid = threadIdx.x;
  const int nb = blockIdx.x * TN;

  const float4* __restrict__ hg = (const float4*)h;
#pragma unroll
  for (int i = 0; i < 8; ++i) {
    const int f = tid + 256 * i;     // 0..2047 float4s of the tile
    const int nd = f >> 5;           // node in tile
    const int k4 = f & 31;           // float4 index in row
    int gn = nb + nd;
    if (gn >= N) gn = N - 1;         // clamped read; stores guarded
    const float4 v = hg[(size_t)gn * 32 + k4];
    float* d = &sh[nd * HSTR + k4 * 4];
    d[0] = v.x; d[1] = v.y; d[2] = v.z; d[3] = v.w;
  }
  __syncthreads();

  const int w = __builtin_amdgcn_readfirstlane(tid >> 6);  // wave id, uniform
  const int l = tid & 63;                                  // lane = node
  const int node = nb + l;
  const float* __restrict__ wb = W + (size_t)(w * 8) * IN_DIM;  // uniform base
  const float* hrow = &sh[l * HSTR];

  float acc[8] = {0.f, 0.f, 0.f, 0.f, 0.f, 0.f, 0.f, 0.f};
#pragma unroll 8
  for (int k = 0; k < IN_DIM; ++k) {
    const float hv = hrow[k];  // bank = (l + k) % 32: conflict-free
#pragma unroll
    for (int j = 0; j < 8; ++j)
      acc[j] = fmaf(hv, wb[j * IN_DIM + k], acc[j]);  // SGPR W operand
  }

  float ssp = 0.f;
#pragma unroll
  for (int j = 0; j < 8; ++j) ssp = fmaf(acc[j], acc[j], ssp);
  ssq[w][l] = ssp;

  if (node < N) {
    float4* zp = (float4*)(z + (size_t)node * OUT_DIM + w * 8);
    zp[0] = make_float4(acc[0], acc[1], acc[2], acc[3]);
    zp[1] = make_float4(acc[4], acc[5], acc[6], acc[7]);
  }
  __syncthreads();
  if (w == 0) {
    const float s = ssq[0][l] + ssq[1][l] + ssq[2][l] + ssq[3][l];
    if (node < N) inv_nrm[node] = 1.0f / fmaxf(sqrtf(s), EPS);
  }
}

// Kernel 2: half-wave per node. Lane l5 = (e = l5>>1, c = l5&1): lane holds
// 16 outputs (chunk c) of src-row e. Dot over 32 dims = 16 fma + ONE swizzle
// (xor1). Softmax denom = 4 swizzles (xor 2/4/8/16 -- all inside the 32-lane
// swizzle domain, zero ds_bpermute). Edge->output transpose via a private
// per-wave LDS slot (4 b128 writes + 16 b32 reads, same-wave: no barrier).
// Scores e = beta*(cos-1) bounded in [-2b,0] -> no max pass needed
// (verified passing R2/R3).
__global__ __launch_bounds__(256) void edge_kernel(
    const float* __restrict__ z, const float* __restrict__ inv_nrm,
    const int* __restrict__ src, const float* __restrict__ beta_p,
    float* __restrict__ out, int N) {
  __shared__ float xp[4 * 2 * DEG * 36];  // 4 waves x 2 nodes x 16e x 36-stride = 18 KB

  const int tid = threadIdx.x;
  const int l = tid & 63, l5 = l & 31, half = l >> 5, wv = tid >> 6;
  const int gw = blockIdx.x * 4 + wv;
  if (gw * 2 >= N) return;            // whole-wave uniform exit
  const int n = gw * 2 + half;
  const int ne = (n < N) ? n : N - 1; // clamp for loads; store guarded
  const int e = l5 >> 1, c = l5 & 1;

  const float beta = *beta_p;
  const int se = src[(size_t)ne * DEG + e];   // pair-dup, coalesced
  const float inv_s = inv_nrm[se];
  const float inv_d = inv_nrm[ne];

  const float4* zs4 = (const float4*)(z + (size_t)se * OUT_DIM + c * 16);
  const float4 v0 = zs4[0], v1 = zs4[1], v2 = zs4[2], v3 = zs4[3];
  const float4* zd4 = (const float4*)(z + (size_t)ne * OUT_DIM + c * 16);
  const float4 d0 = zd4[0], d1 = zd4[1], d2 = zd4[2], d3 = zd4[3];

  float p = v0.x * d0.x;
  p = fmaf(v0.y, d0.y, p); p = fmaf(v0.z, d0.z, p); p = fmaf(v0.w, d0.w, p);
  p = fmaf(v1.x, d1.x, p); p = fmaf(v1.y, d1.y, p); p = fmaf(v1.z, d1.z, p);
  p = fmaf(v1.w, d1.w, p);
  p = fmaf(v2.x, d2.x, p); p = fmaf(v2.y, d2.y, p); p = fmaf(v2.z, d2.z, p);
  p = fmaf(v2.w, d2.w, p);
  p = fmaf(v3.x, d3.x, p); p = fmaf(v3.y, d3.y, p); p = fmaf(v3.z, d3.z, p);
  p = fmaf(v3.w, d3.w, p);
  p += SWZ(p, 0x041F);  // xor1: add other 16-chunk -> full raw dot

  const float cosv = p * inv_s * inv_d;
  const float ex = __expf(beta * (cosv - 1.0f));

  float den = ex;
  den += SWZ(den, 0x081F);  // xor2
  den += SWZ(den, 0x101F);  // xor4
  den += SWZ(den, 0x201F);  // xor8
  den += SWZ(den, 0x401F);  // xor16 -> sum over all 16 edges
  const float rd = 1.0f / den;

  // edge-major -> output-major transpose through private LDS slot
  float* slot = xp + (wv * 2 + half) * (DEG * 36);
  float4* wp = (float4*)(slot + e * 36 + c * 16);
  wp[0] = make_float4(ex * v0.x, ex * v0.y, ex * v0.z, ex * v0.w);
  wp[1] = make_float4(ex * v1.x, ex * v1.y, ex * v1.z, ex * v1.w);
  wp[2] = make_float4(ex * v2.x, ex * v2.y, ex * v2.z, ex * v2.w);
  wp[3] = make_float4(ex * v3.x, ex * v3.y, ex * v3.z, ex * v3.w);
  // same-wave LDS RAW dependency: compiler inserts lgkmcnt wait, no barrier

  float s = 0.f;
#pragma unroll
  for (int e2 = 0; e2 < DEG; ++e2)
    s += slot[e2 * 36 + l5];  // bank = (4*e2 + l5) % 32: conflict-free

  if (n < N) out[(size_t)n * OUT_DIM + l5] = s * rd;  // coalesced 128B/node
}

extern "C" void kernel_launch(void* const* d_in, const int* in_sizes, int n_in,
                              void* d_out, int out_size, void* d_ws, size_t ws_size,
                              hipStream_t stream) {
  const float* h    = (const float*)d_in[0];
  const float* W    = (const float*)d_in[1];
  const float* beta = (const float*)d_in[2];
  const int*   src  = (const int*)d_in[3];
  // d_in[4] = dst == arange(E)//DEG -> node n owns edges [n*DEG, (n+1)*DEG)

  const int N = in_sizes[0] / IN_DIM;

  float* z    = (float*)d_ws;              // N*32 floats = 12.8 MB (raw z)
  float* invn = z + (size_t)N * OUT_DIM;   // N floats

  const int bl1 = (N + TN - 1) / TN;       // 64-node tiles
  gemm_norm_kernel<<<bl1, 256, 0, stream>>>(h, W, z, invn, N);

  const int waves2 = (N + 1) / 2;          // 2 nodes per wave
  const int bl2 = (waves2 + 3) / 4;        // 4 waves per block
  edge_kernel<<<bl2, 256, 0, stream>>>(z, invn, src, beta, (float*)d_out, N);
}